// Round 1
// 148.869 us; speedup vs baseline: 1.0405x; 1.0405x over previous
//
#include <hip/hip_runtime.h>
#include <math.h>

#define T_  2048
#define C_  1024
#define HD_ 64

typedef __attribute__((ext_vector_type(8))) short bf16x8;   // 8 bf16 = 4 VGPRs
typedef __attribute__((ext_vector_type(4))) float f32x4;    // MFMA C/D

#define MFMA_BF16(A, B, C) __builtin_amdgcn_mfma_f32_16x16x32_bf16(A, B, C, 0, 0, 0)

__device__ __forceinline__ short f2bf(float f) {
    union { float f; unsigned u; } v; v.f = f;
    unsigned r = v.u + 0x7fffu + ((v.u >> 16) & 1u);   // RTNE
    return (short)(r >> 16);
}
__device__ __forceinline__ float bf2f(short s) {
    union { float f; unsigned u; } v;
    v.u = ((unsigned)(unsigned short)s) << 16;
    return v.f;
}

// ---------------------------------------------------------------------------
// K0: W[1024][64] fp32  ->  Wt[m][hi/lo][64 h][1024 c] bf16 (transposed+split)
// ---------------------------------------------------------------------------
__global__ __launch_bounds__(256) void prep_w_kernel(
    const float* __restrict__ Wq, const float* __restrict__ Wk,
    const float* __restrict__ Wv, short* __restrict__ wt)
{
    const int m = blockIdx.y;
    const float* W = (m == 0) ? Wq : (m == 1) ? Wk : Wv;
    const int t = threadIdx.x;
    const int c = blockIdx.x * 64 + (t >> 2);
    const int hg = (t & 3) * 16;
    const float4* wp = (const float4*)(W + (size_t)c * HD_ + hg);
    short* hi = wt + (size_t)(m * 2 + 0) * 64 * 1024;
    short* lo = wt + (size_t)(m * 2 + 1) * 64 * 1024;
    #pragma unroll
    for (int u = 0; u < 4; ++u) {
        float4 f = wp[u];
        float vs[4] = {f.x, f.y, f.z, f.w};
        #pragma unroll
        for (int e = 0; e < 4; ++e) {
            int h = hg + u * 4 + e;
            short hh = f2bf(vs[e]);
            hi[(size_t)h * 1024 + c] = hh;
            lo[(size_t)h * 1024 + c] = f2bf(vs[e] - bf2f(hh));
        }
    }
}

// ---------------------------------------------------------------------------
// K1: merged QKV projection (unchanged from 155us version).
// ---------------------------------------------------------------------------
__global__ __launch_bounds__(256) void qkv_proj_kernel(
    const float* __restrict__ x, const short* __restrict__ wt,
    short* __restrict__ qhp, short* __restrict__ qlp,
    short* __restrict__ khp, short* __restrict__ klp,
    short* __restrict__ vtp)
{
    __shared__ __align__(16) short xh[32 * 64], xl[32 * 64];   // 4 KB each
    __shared__ __align__(16) short wh[192 * 64], wl[192 * 64]; // 24 KB each

    const int t = threadIdx.x, L = t & 63, wv = t >> 6;
    const int R0 = blockIdx.x * 32;
    const int xrow = t >> 3, xch = t & 7;

    f32x4 acc[2][3];
    #pragma unroll
    for (int i = 0; i < 2; ++i)
        #pragma unroll
        for (int j = 0; j < 3; ++j) acc[i][j] = {0.f, 0.f, 0.f, 0.f};

    float4 xa0, xa1;
    bf16x8 wr[2][6];
    const float* xp = x + (size_t)(R0 + xrow) * C_ + xch * 8;

    auto loadX = [&](int c0) {
        xa0 = *(const float4*)(xp + c0);
        xa1 = *(const float4*)(xp + c0 + 4);
    };
    auto loadW = [&](int c0) {
        #pragma unroll
        for (int pl = 0; pl < 2; ++pl)
            #pragma unroll
            for (int u = 0; u < 6; ++u) {
                int cc = t + 256 * u;          // 0..1535
                int row = cc >> 3, ch = cc & 7;
                int m = row >> 6, h = row & 63;
                wr[pl][u] = *(const bf16x8*)(wt + (size_t)(m * 2 + pl) * 65536
                                             + (size_t)h * 1024 + c0 + ch * 8);
            }
    };

    loadX(0); loadW(0);
    for (int c0 = 0; c0 < C_; c0 += 64) {
        __syncthreads();
        {   // store x hi/lo
            float vs[8] = {xa0.x, xa0.y, xa0.z, xa0.w, xa1.x, xa1.y, xa1.z, xa1.w};
            bf16x8 vh, vl;
            #pragma unroll
            for (int e = 0; e < 8; ++e) {
                short hh = f2bf(vs[e]);
                vh[e] = hh;
                vl[e] = f2bf(vs[e] - bf2f(hh));
            }
            int slot = (xch ^ (xrow & 7)) * 8;
            *(bf16x8*)&xh[xrow * 64 + slot] = vh;
            *(bf16x8*)&xl[xrow * 64 + slot] = vl;
        }
        {   // store W
            #pragma unroll
            for (int pl = 0; pl < 2; ++pl)
                #pragma unroll
                for (int u = 0; u < 6; ++u) {
                    int cc = t + 256 * u;
                    int row = cc >> 3, ch = cc & 7;
                    short* dst = pl ? wl : wh;
                    *(bf16x8*)&dst[row * 64 + ((ch ^ (row & 7)) * 8)] = wr[pl][u];
                }
        }
        if (c0 + 64 < C_) { loadX(c0 + 64); loadW(c0 + 64); }
        __syncthreads();
        #pragma unroll
        for (int kc = 0; kc < 2; ++kc) {
            const int ch = kc * 4 + (L >> 4);
            bf16x8 axh[2], axl[2], bwh[3], bwl[3];
            #pragma unroll
            for (int rt = 0; rt < 2; ++rt) {
                int row = rt * 16 + (L & 15);
                int off = row * 64 + ((ch ^ (row & 7)) * 8);
                axh[rt] = *(const bf16x8*)&xh[off];
                axl[rt] = *(const bf16x8*)&xl[off];
            }
            #pragma unroll
            for (int cl = 0; cl < 3; ++cl) {
                int ct = wv + cl * 4;          // cl0: q, cl1: k, cl2: v
                int wrow = ct * 16 + (L & 15);
                int off = wrow * 64 + ((ch ^ (wrow & 7)) * 8);
                bwh[cl] = *(const bf16x8*)&wh[off];
                bwl[cl] = *(const bf16x8*)&wl[off];
            }
            #pragma unroll
            for (int rt = 0; rt < 2; ++rt) {
                acc[rt][0] = MFMA_BF16(axl[rt], bwh[0], acc[rt][0]);
                acc[rt][0] = MFMA_BF16(axh[rt], bwl[0], acc[rt][0]);
                acc[rt][0] = MFMA_BF16(axh[rt], bwh[0], acc[rt][0]);
                acc[rt][1] = MFMA_BF16(axl[rt], bwh[1], acc[rt][1]);
                acc[rt][1] = MFMA_BF16(axh[rt], bwl[1], acc[rt][1]);
                acc[rt][1] = MFMA_BF16(axh[rt], bwh[1], acc[rt][1]);
                acc[rt][2] = MFMA_BF16(bwh[2], axh[rt], acc[rt][2]);
            }
        }
    }

    const int quad = L >> 4;
    #pragma unroll
    for (int rt = 0; rt < 2; ++rt) {
        #pragma unroll
        for (int r = 0; r < 4; ++r) {
            int row = R0 + rt * 16 + quad * 4 + r;
            int h = wv * 16 + (L & 15);
            float vq = acc[rt][0][r] * 8.f;
            short hq = f2bf(vq);
            qhp[(size_t)row * HD_ + h] = hq;
            qlp[(size_t)row * HD_ + h] = f2bf(vq - bf2f(hq));
            float vk = acc[rt][1][r];
            short hk = f2bf(vk);
            khp[(size_t)row * HD_ + h] = hk;
            klp[(size_t)row * HD_ + h] = f2bf(vk - bf2f(hk));
            int d = wv * 16 + quad * 4 + r;
            int tt = R0 + rt * 16 + (L & 15);
            int bb = tt >> 11, tl = tt & (T_ - 1);
            vtp[(size_t)(bb * 64 + d) * T_ + tl] = f2bf(acc[rt][2][r]);
        }
    }
}

// ---------------------------------------------------------------------------
// K2a: full-row softmax stats + SCORE SPILL. Block = (b, 64-row tile,
// 256-col segment): grid (32,8,4) = 1024 blocks (4/CU, was 2/CU).
// Staging is prefetched into registers so global-load latency overlaps the
// previous tile's compute. Tiles that the causal PV pass will need
// (col_start <= row_max) are spilled as raw f32 scores to ws (L3-resident);
// pv_kernel no longer recomputes QK^T at all.
// ---------------------------------------------------------------------------
__global__ __launch_bounds__(256) void stats_kernel(
    const short* __restrict__ qhp, const short* __restrict__ qlp,
    const short* __restrict__ khp, const short* __restrict__ klp,
    float* __restrict__ pm, float* __restrict__ sc)
{
    __shared__ __align__(16) short khs[64 * 64], kls[64 * 64];  // 8 KB each
    __shared__ float red[4 * 64 * 2];

    const int t = threadIdx.x, L = t & 63, wv = t >> 6;
    const int bt = blockIdx.x, seg = blockIdx.y, b = blockIdx.z;
    const int R0 = bt * 64, S0 = seg * 256;

    bf16x8 qfh[4][2], qfl[4][2];
    #pragma unroll
    for (int rt = 0; rt < 4; ++rt)
        #pragma unroll
        for (int dc = 0; dc < 2; ++dc) {
            int row = R0 + rt * 16 + (L & 15);
            size_t off = ((size_t)b * T_ + row) * HD_ + dc * 32 + (L >> 4) * 8;
            qfh[rt][dc] = *(const bf16x8*)(qhp + off);
            qfl[rt][dc] = *(const bf16x8*)(qlp + off);
        }

    float ml[4][4], ll[4][4];
    #pragma unroll
    for (int rt = 0; rt < 4; ++rt)
        #pragma unroll
        for (int r = 0; r < 4; ++r) { ml[rt][r] = -1e30f; ll[rt][r] = 0.f; }

    const int pl = t >> 7, id = t & 127;
    const short* ksrc = pl ? klp : khp;
    short* kdst = pl ? kls : khs;
    bf16x8 kr[4];
    auto loadK = [&](int jt) {
        #pragma unroll
        for (int u = 0; u < 4; ++u) {
            int cid = id * 4 + u;              // 0..511
            int col = cid >> 3, ch = cid & 7;
            kr[u] = *(const bf16x8*)(ksrc
                + ((size_t)b * T_ + S0 + jt * 64 + col) * HD_ + ch * 8);
        }
    };

    loadK(0);
    for (int jt = 0; jt < 4; ++jt) {
        __syncthreads();
        #pragma unroll
        for (int u = 0; u < 4; ++u) {
            int cid = id * 4 + u;
            int col = cid >> 3, ch = cid & 7;
            *(bf16x8*)&kdst[col * 64 + ((ch ^ (col & 7)) * 8)] = kr[u];
        }
        __syncthreads();
        if (jt < 3) loadK(jt + 1);             // prefetch: latency under compute
        const int colL = wv * 16 + (L & 15);
        bf16x8 kf[2], kfl[2];
        #pragma unroll
        for (int dc = 0; dc < 2; ++dc) {
            int ch = dc * 4 + (L >> 4);
            int off = colL * 64 + ((ch ^ (colL & 7)) * 8);
            kf[dc]  = *(const bf16x8*)&khs[off];
            kfl[dc] = *(const bf16x8*)&kls[off];
        }
        const bool doStore = (S0 + jt * 64) <= (R0 + 63);   // causal-needed tile
        #pragma unroll
        for (int rt = 0; rt < 4; ++rt) {
            f32x4 s = {0.f, 0.f, 0.f, 0.f};
            #pragma unroll
            for (int dc = 0; dc < 2; ++dc) {
                s = MFMA_BF16(qfl[rt][dc], kf[dc], s);
                s = MFMA_BF16(qfh[rt][dc], kfl[dc], s);
                s = MFMA_BF16(qfh[rt][dc], kf[dc], s);
            }
            if (doStore) {
                #pragma unroll
                for (int r = 0; r < 4; ++r) {
                    int row = R0 + rt * 16 + (L >> 4) * 4 + r;
                    sc[((size_t)b * T_ + row) * T_ + S0 + jt * 64 + colL] = s[r];
                }
            }
            #pragma unroll
            for (int r = 0; r < 4; ++r) {
                float mn = fmaxf(ml[rt][r], s[r]);
                ll[rt][r] = ll[rt][r] * __expf(ml[rt][r] - mn) + __expf(s[r] - mn);
                ml[rt][r] = mn;
            }
        }
    }
    // merge the 16 columns within each wave
    #pragma unroll
    for (int off = 1; off < 16; off <<= 1)
        #pragma unroll
        for (int rt = 0; rt < 4; ++rt)
            #pragma unroll
            for (int r = 0; r < 4; ++r) {
                float mo = __shfl_xor(ml[rt][r], off, 64);
                float lo = __shfl_xor(ll[rt][r], off, 64);
                float mn = fmaxf(ml[rt][r], mo);
                ll[rt][r] = ll[rt][r] * __expf(ml[rt][r] - mn) + lo * __expf(mo - mn);
                ml[rt][r] = mn;
            }
    if ((L & 15) == 0) {
        #pragma unroll
        for (int rt = 0; rt < 4; ++rt)
            #pragma unroll
            for (int r = 0; r < 4; ++r) {
                int row = rt * 16 + (L >> 4) * 4 + r;
                red[(wv * 64 + row) * 2 + 0] = ml[rt][r];
                red[(wv * 64 + row) * 2 + 1] = ll[rt][r];
            }
    }
    __syncthreads();
    if (t < 64) {
        float M = red[t * 2], S = red[t * 2 + 1];
        #pragma unroll
        for (int w = 1; w < 4; ++w) {
            float mo = red[(w * 64 + t) * 2], lo = red[(w * 64 + t) * 2 + 1];
            float mn = fmaxf(M, mo);
            S = S * __expf(M - mn) + lo * __expf(mo - mn);
            M = mn;
        }
        size_t o = ((size_t)((b * 32 + bt) * 8 + seg) * 64 + t) * 2;
        pm[o] = M;
        pm[o + 1] = S;
    }
}

// ---------------------------------------------------------------------------
// K2b: merge the 8 segment partials -> m, 1/l per row.
// ---------------------------------------------------------------------------
__global__ __launch_bounds__(256) void stat_merge_kernel(
    const float* __restrict__ pm, float* __restrict__ msp, float* __restrict__ ilp)
{
    int gid = blockIdx.x * 256 + threadIdx.x;     // 0..8191
    int b = gid >> 11, rl = gid & 2047, bt = rl >> 6, rr = rl & 63;
    float M = -1e30f, S = 0.f;
    #pragma unroll
    for (int seg = 0; seg < 8; ++seg) {
        size_t o = ((size_t)((b * 32 + bt) * 8 + seg) * 64 + rr) * 2;
        float mo = pm[o], lo = pm[o + 1];
        float mn = fmaxf(M, mo);
        S = S * __expf(M - mn) + lo * __expf(mo - mn);
        M = mn;
    }
    msp[gid] = M;
    ilp[gid] = 1.f / S;
}

// ---------------------------------------------------------------------------
// K2c: causal second softmax + PV, streaming from spilled scores.
// Block = (b, 16-row tile p), 256 thr = 4 waves (wave = 32-col chunk).
// NO LDS staging, NO barriers in the main loop, NO QK^T recompute:
//  - A-fragment (ev): lane&15 = row, (lane>>4)*8+e = k  ->  each lane reads
//    its own score row at a contiguous 32B chunk; the wave's 64 lanes cover
//    16 rows x one 128B-aligned line each (fully coalesced).
//  - B-fragment (V): vt is [d][t], so lane's 8 k-elements are one bf16x8.
// Garbage beyond the spilled causal tiles is masked (ev := 0) before use.
// Tiles dispatched longest-first (p = 127 - idx) for makespan.
// ---------------------------------------------------------------------------
__global__ __launch_bounds__(256) void pv_kernel(
    const float* __restrict__ sc, const short* __restrict__ vtp,
    const float* __restrict__ msp, const float* __restrict__ ilp,
    float* __restrict__ out)
{
    __shared__ float ored[4][16][64];   // 16 KB: per-wave PV partials
    __shared__ float dred[4][16];       // per-wave denominator partials

    const int t = threadIdx.x, L = t & 63, wv = t >> 6;
    const int b = blockIdx.x & 3;
    const int p = 127 - (blockIdx.x >> 2);
    const int T0 = p * 16;
    const int row = T0 + (L & 15);

    const float ms = msp[b * T_ + row];
    const float is = ilp[b * T_ + row];
    const float* srow = sc + ((size_t)b * T_ + row) * T_;
    const short* vb = vtp + (size_t)b * 64 * T_;
    const int nJ = (T0 + 143) >> 7;     // ceil((T0+16)/128)
    const int cq = (L >> 4) * 8;

    f32x4 ov[4];
    #pragma unroll
    for (int dt = 0; dt < 4; ++dt) ov[dt] = {0.f, 0.f, 0.f, 0.f};
    float dn = 0.f;

    for (int jt = 0; jt < nJ; ++jt) {
        const int c0 = jt * 128 + wv * 32 + cq;
        float4 s0 = *(const float4*)(srow + c0);
        float4 s1 = *(const float4*)(srow + c0 + 4);
        float vs[8] = {s0.x, s0.y, s0.z, s0.w, s1.x, s1.y, s1.z, s1.w};
        bf16x8 ef;
        #pragma unroll
        for (int e = 0; e < 8; ++e) {
            float pvv = __expf(vs[e] - ms) * is;            // first softmax
            float evv = (c0 + e <= row) ? __expf(pvv) : 0.f; // causal + 2nd exp
            dn += evv;
            ef[e] = f2bf(evv);
        }
        #pragma unroll
        for (int dt = 0; dt < 4; ++dt) {
            bf16x8 vf = *(const bf16x8*)(vb + (size_t)(dt * 16 + (L & 15)) * T_ + c0);
            ov[dt] = MFMA_BF16(ef, vf, ov[dt]);
        }
    }

    // row denominator: combine the 4 chunk-lanes holding the same row
    dn += __shfl_xor(dn, 16, 64);
    dn += __shfl_xor(dn, 32, 64);
    if (L < 16) dred[wv][L] = dn;
    #pragma unroll
    for (int dt = 0; dt < 4; ++dt)
        #pragma unroll
        for (int r = 0; r < 4; ++r)
            ored[wv][(L >> 4) * 4 + r][dt * 16 + (L & 15)] = ov[dt][r];
    __syncthreads();

    // 256 threads -> 16 rows x 64 d, float4 per thread, coalesced
    const int orow = t >> 4, d0 = (t & 15) * 4;
    float D = dred[0][orow] + dred[1][orow] + dred[2][orow] + dred[3][orow];
    float di = 1.f / D;
    float4 o;
    o.x = (ored[0][orow][d0 + 0] + ored[1][orow][d0 + 0]
         + ored[2][orow][d0 + 0] + ored[3][orow][d0 + 0]) * di;
    o.y = (ored[0][orow][d0 + 1] + ored[1][orow][d0 + 1]
         + ored[2][orow][d0 + 1] + ored[3][orow][d0 + 1]) * di;
    o.z = (ored[0][orow][d0 + 2] + ored[1][orow][d0 + 2]
         + ored[2][orow][d0 + 2] + ored[3][orow][d0 + 2]) * di;
    o.w = (ored[0][orow][d0 + 3] + ored[1][orow][d0 + 3]
         + ored[2][orow][d0 + 3] + ored[3][orow][d0 + 3]) * di;
    *(float4*)(out + ((size_t)b * T_ + T0 + orow) * HD_ + d0) = o;
}

// ---------------------------------------------------------------------------
extern "C" void kernel_launch(void* const* d_in, const int* in_sizes, int n_in,
                              void* d_out, int out_size, void* d_ws, size_t ws_size,
                              hipStream_t stream) {
    (void)in_sizes; (void)n_in; (void)out_size; (void)ws_size;
    const float* x  = (const float*)d_in[0];
    const float* Wq = (const float*)d_in[1];
    const float* Wk = (const float*)d_in[2];
    const float* Wv = (const float*)d_in[3];
    float* outp = (float*)d_out;

    // ws layout (ws_size = 256 MiB per harness fill of 262144 KB):
    //   [0, 768K)        wt   (W transposed hi/lo; dead after proj)
    //   [0, 512K)        pm   (stats partials, 8 segs; reuses wt region)
    //   [512K, 544K)     msp  [544K, 576K) ilp
    //   [768K, 5.75M)    qh/ql/kh/kl/vt
    //   [8M, 72M)        sc   scores f32 [4][2048][2048] (L3-resident)
    char* ws = (char*)d_ws;
    short* wt  = (short*)ws;
    float* pm  = (float*)ws;
    float* msp = (float*)(ws + 524288);
    float* ilp = (float*)(ws + 557056);
    short* qh = (short*)(ws + 786432);
    short* ql = (short*)(ws + 786432 + 1048576);
    short* kh = (short*)(ws + 786432 + 2 * 1048576);
    short* kl = (short*)(ws + 786432 + 3 * 1048576);
    short* vt = (short*)(ws + 786432 + 4 * 1048576);
    float* sc = (float*)(ws + 8388608);

    prep_w_kernel<<<dim3(16, 3), 256, 0, stream>>>(Wq, Wk, Wv, wt);
    qkv_proj_kernel<<<dim3(256), 256, 0, stream>>>(x, wt, qh, ql, kh, kl, vt);
    stats_kernel<<<dim3(32, 8, 4), 256, 0, stream>>>(qh, ql, kh, kl, pm, sc);
    stat_merge_kernel<<<dim3(32), 256, 0, stream>>>(pm, msp, ilp);
    pv_kernel<<<dim3(512), 256, 0, stream>>>(sc, vt, msp, ilp, outp);
}

// Round 2
// 139.877 us; speedup vs baseline: 1.1074x; 1.0643x over previous
//
#include <hip/hip_runtime.h>
#include <math.h>

#define T_  2048
#define C_  1024
#define HD_ 64

typedef __attribute__((ext_vector_type(8))) short bf16x8;   // 8 bf16 = 4 VGPRs
typedef __attribute__((ext_vector_type(4))) float f32x4;    // MFMA C/D

#define MFMA_BF16(A, B, C) __builtin_amdgcn_mfma_f32_16x16x32_bf16(A, B, C, 0, 0, 0)

__device__ __forceinline__ short f2bf(float f) {
    union { float f; unsigned u; } v; v.f = f;
    unsigned r = v.u + 0x7fffu + ((v.u >> 16) & 1u);   // RTNE
    return (short)(r >> 16);
}
__device__ __forceinline__ float bf2f(short s) {
    union { float f; unsigned u; } v;
    v.u = ((unsigned)(unsigned short)s) << 16;
    return v.f;
}

// ---------------------------------------------------------------------------
// K0: W[1024][64] fp32 -> wtf in MFMA B-FRAGMENT order (hi/lo planes).
// Fragment index: (((ct*2 + pl)*16 + c0i)*2 + kc)*64 + L, 8 bf16 elems each.
//   ct = m*4 + (h>>4)  (q: 0-3, k: 4-7, v: 8-11)
//   element e of lane L = W_m[h=(ct&3)*16+(L&15)][c = c0i*64 + kc*32 + (L>>4)*8 + e]
// qkv then loads B-operands as ONE coalesced bf16x8 per lane -- no LDS for W.
// ---------------------------------------------------------------------------
__global__ __launch_bounds__(256) void prep_w_kernel(
    const float* __restrict__ Wq, const float* __restrict__ Wk,
    const float* __restrict__ Wv, short* __restrict__ wtf)
{
    const int m = blockIdx.y;
    const float* W = (m == 0) ? Wq : (m == 1) ? Wk : Wv;
    const int t = threadIdx.x;
    const int c = blockIdx.x * 64 + (t >> 2);
    const int hg = (t & 3) * 16;
    const int ct = m * 4 + (t & 3);
    const int c0i = c >> 6, kc = (c >> 5) & 1, lq = (c >> 3) & 3, e = c & 7;
    const float4* wp = (const float4*)(W + (size_t)c * HD_ + hg);
    #pragma unroll
    for (int u = 0; u < 4; ++u) {
        float4 f = wp[u];
        float vs[4] = {f.x, f.y, f.z, f.w};
        #pragma unroll
        for (int ei = 0; ei < 4; ++ei) {
            int h16 = u * 4 + ei;              // h & 15
            int L = h16 + 16 * lq;
            short hh = f2bf(vs[ei]);
            short lo = f2bf(vs[ei] - bf2f(hh));
            size_t oh = ((((size_t)(ct * 2 + 0) * 16 + c0i) * 2 + kc) * 64 + L) * 8 + e;
            size_t ol = ((((size_t)(ct * 2 + 1) * 16 + c0i) * 2 + kc) * 64 + L) * 8 + e;
            wtf[oh] = hh;
            wtf[ol] = lo;
        }
    }
}

// ---------------------------------------------------------------------------
// K1: merged QKV projection. 256 blocks x 512 thr (8 waves = 2/SIMD).
// Waves 0-3: rows 0-15, waves 4-7: rows 16-31; ctq = wv&3 picks the 16-col
// tile of each of q,k,v. W operands are direct global fragment loads
// (register double-buffered); only x goes through LDS (8 KB).
// ---------------------------------------------------------------------------
__global__ __launch_bounds__(512) void qkv_proj_kernel(
    const float* __restrict__ x, const short* __restrict__ wtf,
    short* __restrict__ qhp, short* __restrict__ qlp,
    short* __restrict__ khp, short* __restrict__ klp,
    short* __restrict__ vtp)
{
    __shared__ __align__(16) short xh[32 * 64], xl[32 * 64];   // 4 KB each

    const int t = threadIdx.x, L = t & 63, wv = t >> 6;
    const int R0 = blockIdx.x * 32;
    const int rtb = (wv >> 2) * 16;        // wave's row-tile base (0 or 16)
    const int ctq = wv & 3;                // wave's 16-col tile

    f32x4 acc[3];
    #pragma unroll
    for (int j = 0; j < 3; ++j) acc[j] = {0.f, 0.f, 0.f, 0.f};

    // x staging: 32 rows x 64 cols fp32 per step; thread = one float4
    const int xrow = t >> 4, xc4 = t & 15;
    const float* xp = x + (size_t)(R0 + xrow) * C_ + xc4 * 4;
    float4 xa;
    auto loadX = [&](int c0) { xa = *(const float4*)(xp + c0); };

    // W fragments: slots 0=qh 1=ql 2=kh 3=kl 4=vh
    const size_t lo8 = (size_t)L * 8;
    auto loadWF = [&](int c0i, int kc, bf16x8* w) {
        w[0] = *(const bf16x8*)(wtf + (size_t)((((ctq + 0) * 2 + 0) * 16 + c0i) * 2 + kc) * 512 + lo8);
        w[1] = *(const bf16x8*)(wtf + (size_t)((((ctq + 0) * 2 + 1) * 16 + c0i) * 2 + kc) * 512 + lo8);
        w[2] = *(const bf16x8*)(wtf + (size_t)((((ctq + 4) * 2 + 0) * 16 + c0i) * 2 + kc) * 512 + lo8);
        w[3] = *(const bf16x8*)(wtf + (size_t)((((ctq + 4) * 2 + 1) * 16 + c0i) * 2 + kc) * 512 + lo8);
        w[4] = *(const bf16x8*)(wtf + (size_t)((((ctq + 8) * 2 + 0) * 16 + c0i) * 2 + kc) * 512 + lo8);
    };

    bf16x8 wf0[5], wf1[5];
    loadX(0);
    loadWF(0, 0, wf0);

    const int c8 = xc4 >> 1, xhalf = xc4 & 1;
    const int arow = rtb + (L & 15);

    for (int c0i = 0; c0i < 16; ++c0i) {
        __syncthreads();
        {   // stage x hi/lo (4 elems per thread)
            float vs[4] = {xa.x, xa.y, xa.z, xa.w};
            short4 vh, vl;
            short* vhp = (short*)&vh; short* vlp = (short*)&vl;
            #pragma unroll
            for (int e = 0; e < 4; ++e) {
                short hh = f2bf(vs[e]);
                vhp[e] = hh;
                vlp[e] = f2bf(vs[e] - bf2f(hh));
            }
            int slot = xrow * 64 + ((c8 ^ (xrow & 7)) * 8) + xhalf * 4;
            *(short4*)&xh[slot] = vh;
            *(short4*)&xl[slot] = vl;
        }
        if (c0i < 15) loadX((c0i + 1) * 64);
        __syncthreads();

        // ---- kc = 0: compute with wf0, prefetch wf1
        loadWF(c0i, 1, wf1);
        {
            int ch = 0 * 4 + (L >> 4);
            int off = arow * 64 + ((ch ^ (arow & 7)) * 8);
            bf16x8 axh = *(const bf16x8*)&xh[off];
            bf16x8 axl = *(const bf16x8*)&xl[off];
            acc[0] = MFMA_BF16(axl, wf0[0], acc[0]);
            acc[0] = MFMA_BF16(axh, wf0[1], acc[0]);
            acc[0] = MFMA_BF16(axh, wf0[0], acc[0]);
            acc[1] = MFMA_BF16(axl, wf0[2], acc[1]);
            acc[1] = MFMA_BF16(axh, wf0[3], acc[1]);
            acc[1] = MFMA_BF16(axh, wf0[2], acc[1]);
            acc[2] = MFMA_BF16(wf0[4], axh, acc[2]);   // v swapped -> D[h][t]
        }
        // ---- kc = 1: compute with wf1, prefetch next step's wf0
        if (c0i < 15) loadWF(c0i + 1, 0, wf0);
        {
            int ch = 1 * 4 + (L >> 4);
            int off = arow * 64 + ((ch ^ (arow & 7)) * 8);
            bf16x8 axh = *(const bf16x8*)&xh[off];
            bf16x8 axl = *(const bf16x8*)&xl[off];
            acc[0] = MFMA_BF16(axl, wf1[0], acc[0]);
            acc[0] = MFMA_BF16(axh, wf1[1], acc[0]);
            acc[0] = MFMA_BF16(axh, wf1[0], acc[0]);
            acc[1] = MFMA_BF16(axl, wf1[2], acc[1]);
            acc[1] = MFMA_BF16(axh, wf1[3], acc[1]);
            acc[1] = MFMA_BF16(axh, wf1[2], acc[1]);
            acc[2] = MFMA_BF16(wf1[4], axh, acc[2]);
        }
    }

    // ---- epilogue
    const int quad = L >> 4;
    #pragma unroll
    for (int r = 0; r < 4; ++r) {
        int row = R0 + rtb + quad * 4 + r;
        int h = ctq * 16 + (L & 15);
        float vq = acc[0][r] * 8.f;
        short hq = f2bf(vq);
        qhp[(size_t)row * HD_ + h] = hq;
        qlp[(size_t)row * HD_ + h] = f2bf(vq - bf2f(hq));
        float vk = acc[1][r];
        short hk = f2bf(vk);
        khp[(size_t)row * HD_ + h] = hk;
        klp[(size_t)row * HD_ + h] = f2bf(vk - bf2f(hk));
        int d = ctq * 16 + quad * 4 + r;
        int tt = R0 + rtb + (L & 15);
        int bb = tt >> 11, tl = tt & (T_ - 1);
        vtp[(size_t)(bb * 64 + d) * T_ + tl] = f2bf(acc[2][r]);
    }
}

// ---------------------------------------------------------------------------
// K2a: full-row softmax stats + score spill. NO LDS staging: K B-fragments
// load straight from global (identical per-lane values and identical global
// traffic as via LDS; L1 serves the 16 KB tile). Zero barriers in the jt
// loop; K frags register double-buffered. Causal-needed tiles spilled f32.
// ---------------------------------------------------------------------------
__global__ __launch_bounds__(256) void stats_kernel(
    const short* __restrict__ qhp, const short* __restrict__ qlp,
    const short* __restrict__ khp, const short* __restrict__ klp,
    float* __restrict__ pm, float* __restrict__ sc)
{
    __shared__ float red[4 * 64 * 2];

    const int t = threadIdx.x, L = t & 63, wv = t >> 6;
    const int bt = blockIdx.x, seg = blockIdx.y, b = blockIdx.z;
    const int R0 = bt * 64, S0 = seg * 256;

    bf16x8 qfh[4][2], qfl[4][2];
    #pragma unroll
    for (int rt = 0; rt < 4; ++rt)
        #pragma unroll
        for (int dc = 0; dc < 2; ++dc) {
            int row = R0 + rt * 16 + (L & 15);
            size_t off = ((size_t)b * T_ + row) * HD_ + dc * 32 + (L >> 4) * 8;
            qfh[rt][dc] = *(const bf16x8*)(qhp + off);
            qfl[rt][dc] = *(const bf16x8*)(qlp + off);
        }

    float ml[4][4], ll[4][4];
    #pragma unroll
    for (int rt = 0; rt < 4; ++rt)
        #pragma unroll
        for (int r = 0; r < 4; ++r) { ml[rt][r] = -1e30f; ll[rt][r] = 0.f; }

    const int colL = wv * 16 + (L & 15);
    const short* kbh = khp + ((size_t)b * T_ + S0 + colL) * HD_;
    const short* kbl = klp + ((size_t)b * T_ + S0 + colL) * HD_;
    const int cho = (L >> 4) * 8;

    bf16x8 kfh[2][2], kfl[2][2];
    auto loadK = [&](int jt, bf16x8 kh[2], bf16x8 kl[2]) {
        #pragma unroll
        for (int dc = 0; dc < 2; ++dc) {
            kh[dc] = *(const bf16x8*)(kbh + (size_t)jt * 64 * HD_ + dc * 32 + cho);
            kl[dc] = *(const bf16x8*)(kbl + (size_t)jt * 64 * HD_ + dc * 32 + cho);
        }
    };
    loadK(0, kfh[0], kfl[0]);

    #pragma unroll
    for (int jt = 0; jt < 4; ++jt) {
        const int cb = jt & 1;
        if (jt < 3) loadK(jt + 1, kfh[cb ^ 1], kfl[cb ^ 1]);
        const bool doStore = (S0 + jt * 64) <= (R0 + 63);   // causal-needed tile
        #pragma unroll
        for (int rt = 0; rt < 4; ++rt) {
            f32x4 s = {0.f, 0.f, 0.f, 0.f};
            #pragma unroll
            for (int dc = 0; dc < 2; ++dc) {
                s = MFMA_BF16(qfl[rt][dc], kfh[cb][dc], s);
                s = MFMA_BF16(qfh[rt][dc], kfl[cb][dc], s);
                s = MFMA_BF16(qfh[rt][dc], kfh[cb][dc], s);
            }
            if (doStore) {
                #pragma unroll
                for (int r = 0; r < 4; ++r) {
                    int row = R0 + rt * 16 + (L >> 4) * 4 + r;
                    sc[((size_t)b * T_ + row) * T_ + S0 + jt * 64 + colL] = s[r];
                }
            }
            #pragma unroll
            for (int r = 0; r < 4; ++r) {
                float mn = fmaxf(ml[rt][r], s[r]);
                ll[rt][r] = ll[rt][r] * __expf(ml[rt][r] - mn) + __expf(s[r] - mn);
                ml[rt][r] = mn;
            }
        }
    }
    // merge the 16 columns within each wave
    #pragma unroll
    for (int off = 1; off < 16; off <<= 1)
        #pragma unroll
        for (int rt = 0; rt < 4; ++rt)
            #pragma unroll
            for (int r = 0; r < 4; ++r) {
                float mo = __shfl_xor(ml[rt][r], off, 64);
                float lo = __shfl_xor(ll[rt][r], off, 64);
                float mn = fmaxf(ml[rt][r], mo);
                ll[rt][r] = ll[rt][r] * __expf(ml[rt][r] - mn) + lo * __expf(mo - mn);
                ml[rt][r] = mn;
            }
    if ((L & 15) == 0) {
        #pragma unroll
        for (int rt = 0; rt < 4; ++rt)
            #pragma unroll
            for (int r = 0; r < 4; ++r) {
                int row = rt * 16 + (L >> 4) * 4 + r;
                red[(wv * 64 + row) * 2 + 0] = ml[rt][r];
                red[(wv * 64 + row) * 2 + 1] = ll[rt][r];
            }
    }
    __syncthreads();
    if (t < 64) {
        float M = red[t * 2], S = red[t * 2 + 1];
        #pragma unroll
        for (int w = 1; w < 4; ++w) {
            float mo = red[(w * 64 + t) * 2], lo = red[(w * 64 + t) * 2 + 1];
            float mn = fmaxf(M, mo);
            S = S * __expf(M - mn) + lo * __expf(mo - mn);
            M = mn;
        }
        size_t o = ((size_t)((b * 32 + bt) * 8 + seg) * 64 + t) * 2;
        pm[o] = M;
        pm[o + 1] = S;
    }
}

// ---------------------------------------------------------------------------
// K2c: causal second softmax + PV, streaming spilled scores. stat_merge is
// FOLDED into the prologue (t<16 merges the 8 segment partials for this
// block's rows). Block->tile map pairs long+short tiles on the same CU:
// i<64 -> p=127-i (long half first), i>=64 -> p=i-64.
// ---------------------------------------------------------------------------
__global__ __launch_bounds__(256) void pv_kernel(
    const float* __restrict__ sc, const short* __restrict__ vtp,
    const float* __restrict__ pm, float* __restrict__ out)
{
    __shared__ float ored[4][16][64];   // 16 KB: per-wave PV partials
    __shared__ float dred[4][16];
    __shared__ float msl[16], isl[16];

    const int t = threadIdx.x, L = t & 63, wv = t >> 6;
    const int b = blockIdx.x & 3;
    const int i = blockIdx.x >> 2;
    const int p = (i < 64) ? (127 - i) : (i - 64);
    const int T0 = p * 16;

    if (t < 16) {                       // folded stat_merge for these 16 rows
        int row = T0 + t;
        int bt = row >> 6, rr = row & 63;
        float M = -1e30f, S = 0.f;
        #pragma unroll
        for (int seg = 0; seg < 8; ++seg) {
            size_t o = ((size_t)((b * 32 + bt) * 8 + seg) * 64 + rr) * 2;
            float mo = pm[o], lo = pm[o + 1];
            float mn = fmaxf(M, mo);
            S = S * __expf(M - mn) + lo * __expf(mo - mn);
            M = mn;
        }
        msl[t] = M;
        isl[t] = 1.f / S;
    }
    __syncthreads();

    const int row = T0 + (L & 15);
    const float ms = msl[L & 15];
    const float is = isl[L & 15];
    const float* srow = sc + ((size_t)b * T_ + row) * T_;
    const short* vb = vtp + (size_t)b * 64 * T_;
    const int nJ = (T0 + 143) >> 7;     // ceil((T0+16)/128)
    const int cq = (L >> 4) * 8;

    f32x4 ov[4];
    #pragma unroll
    for (int dt = 0; dt < 4; ++dt) ov[dt] = {0.f, 0.f, 0.f, 0.f};
    float dn = 0.f;

    for (int jt = 0; jt < nJ; ++jt) {
        const int c0 = jt * 128 + wv * 32 + cq;
        float4 s0 = *(const float4*)(srow + c0);
        float4 s1 = *(const float4*)(srow + c0 + 4);
        float vs[8] = {s0.x, s0.y, s0.z, s0.w, s1.x, s1.y, s1.z, s1.w};
        bf16x8 ef;
        #pragma unroll
        for (int e = 0; e < 8; ++e) {
            float pvv = __expf(vs[e] - ms) * is;             // first softmax
            float evv = (c0 + e <= row) ? __expf(pvv) : 0.f; // causal + 2nd exp
            dn += evv;
            ef[e] = f2bf(evv);
        }
        #pragma unroll
        for (int dt = 0; dt < 4; ++dt) {
            bf16x8 vf = *(const bf16x8*)(vb + (size_t)(dt * 16 + (L & 15)) * T_ + c0);
            ov[dt] = MFMA_BF16(ef, vf, ov[dt]);
        }
    }

    dn += __shfl_xor(dn, 16, 64);
    dn += __shfl_xor(dn, 32, 64);
    if (L < 16) dred[wv][L] = dn;
    #pragma unroll
    for (int dt = 0; dt < 4; ++dt)
        #pragma unroll
        for (int r = 0; r < 4; ++r)
            ored[wv][(L >> 4) * 4 + r][dt * 16 + (L & 15)] = ov[dt][r];
    __syncthreads();

    const int orow = t >> 4, d0 = (t & 15) * 4;
    float D = dred[0][orow] + dred[1][orow] + dred[2][orow] + dred[3][orow];
    float di = 1.f / D;
    float4 o;
    o.x = (ored[0][orow][d0 + 0] + ored[1][orow][d0 + 0]
         + ored[2][orow][d0 + 0] + ored[3][orow][d0 + 0]) * di;
    o.y = (ored[0][orow][d0 + 1] + ored[1][orow][d0 + 1]
         + ored[2][orow][d0 + 1] + ored[3][orow][d0 + 1]) * di;
    o.z = (ored[0][orow][d0 + 2] + ored[1][orow][d0 + 2]
         + ored[2][orow][d0 + 2] + ored[3][orow][d0 + 2]) * di;
    o.w = (ored[0][orow][d0 + 3] + ored[1][orow][d0 + 3]
         + ored[2][orow][d0 + 3] + ored[3][orow][d0 + 3]) * di;
    *(float4*)(out + ((size_t)b * T_ + T0 + orow) * HD_ + d0) = o;
}

// ---------------------------------------------------------------------------
extern "C" void kernel_launch(void* const* d_in, const int* in_sizes, int n_in,
                              void* d_out, int out_size, void* d_ws, size_t ws_size,
                              hipStream_t stream) {
    (void)in_sizes; (void)n_in; (void)out_size; (void)ws_size;
    const float* x  = (const float*)d_in[0];
    const float* Wq = (const float*)d_in[1];
    const float* Wk = (const float*)d_in[2];
    const float* Wv = (const float*)d_in[3];
    float* outp = (float*)d_out;

    // ws layout:
    //   [0, 768K)        wt   (W fragment buffer; dead after proj)
    //   [0, 512K)        pm   (stats partials, 8 segs; reuses wt region)
    //   [768K, 5.75M)    qh/ql/kh/kl/vt
    //   [8M, 72M)        sc   scores f32 [4][2048][2048] (L3-resident)
    char* ws = (char*)d_ws;
    short* wt  = (short*)ws;
    float* pm  = (float*)ws;
    short* qh = (short*)(ws + 786432);
    short* ql = (short*)(ws + 786432 + 1048576);
    short* kh = (short*)(ws + 786432 + 2 * 1048576);
    short* kl = (short*)(ws + 786432 + 3 * 1048576);
    short* vt = (short*)(ws + 786432 + 4 * 1048576);
    float* sc = (float*)(ws + 8388608);

    prep_w_kernel<<<dim3(16, 3), 256, 0, stream>>>(Wq, Wk, Wv, wt);
    qkv_proj_kernel<<<dim3(256), 512, 0, stream>>>(x, wt, qh, ql, kh, kl, vt);
    stats_kernel<<<dim3(32, 8, 4), 256, 0, stream>>>(qh, ql, kh, kl, pm, sc);
    pv_kernel<<<dim3(512), 256, 0, stream>>>(sc, vt, pm, outp);
}

// Round 3
// 135.126 us; speedup vs baseline: 1.1463x; 1.0352x over previous
//
#include <hip/hip_runtime.h>
#include <math.h>

#define T_  2048
#define C_  1024
#define HD_ 64

typedef __attribute__((ext_vector_type(8))) short bf16x8;   // 8 bf16 = 4 VGPRs
typedef __attribute__((ext_vector_type(4))) float f32x4;    // MFMA C/D

#define MFMA_BF16(A, B, C) __builtin_amdgcn_mfma_f32_16x16x32_bf16(A, B, C, 0, 0, 0)

__device__ __forceinline__ short f2bf(float f) {
    union { float f; unsigned u; } v; v.f = f;
    unsigned r = v.u + 0x7fffu + ((v.u >> 16) & 1u);   // RTNE
    return (short)(r >> 16);
}
__device__ __forceinline__ float bf2f(short s) {
    union { float f; unsigned u; } v;
    v.u = ((unsigned)(unsigned short)s) << 16;
    return v.f;
}

// ---------------------------------------------------------------------------
// K0: W[1024][64] fp32 -> wtf in MFMA B-FRAGMENT order (hi/lo planes).
// Fragment index: (((ct*2 + pl)*16 + c0i)*2 + kc)*64 + L, 8 bf16 elems each.
//   ct = m*4 + (h>>4)  (q: 0-3, k: 4-7, v: 8-11)
//   element e of lane L = W_m[h=(ct&3)*16+(L&15)][c = c0i*64 + kc*32 + (L>>4)*8 + e]
// ---------------------------------------------------------------------------
__global__ __launch_bounds__(256) void prep_w_kernel(
    const float* __restrict__ Wq, const float* __restrict__ Wk,
    const float* __restrict__ Wv, short* __restrict__ wtf)
{
    const int m = blockIdx.y;
    const float* W = (m == 0) ? Wq : (m == 1) ? Wk : Wv;
    const int t = threadIdx.x;
    const int c = blockIdx.x * 64 + (t >> 2);
    const int hg = (t & 3) * 16;
    const int ct = m * 4 + (t & 3);
    const int c0i = c >> 6, kc = (c >> 5) & 1, lq = (c >> 3) & 3, e = c & 7;
    const float4* wp = (const float4*)(W + (size_t)c * HD_ + hg);
    #pragma unroll
    for (int u = 0; u < 4; ++u) {
        float4 f = wp[u];
        float vs[4] = {f.x, f.y, f.z, f.w};
        #pragma unroll
        for (int ei = 0; ei < 4; ++ei) {
            int h16 = u * 4 + ei;              // h & 15
            int L = h16 + 16 * lq;
            short hh = f2bf(vs[ei]);
            short lo = f2bf(vs[ei] - bf2f(hh));
            size_t oh = ((((size_t)(ct * 2 + 0) * 16 + c0i) * 2 + kc) * 64 + L) * 8 + e;
            size_t ol = ((((size_t)(ct * 2 + 1) * 16 + c0i) * 2 + kc) * 64 + L) * 8 + e;
            wtf[oh] = hh;
            wtf[ol] = lo;
        }
    }
}

// ---------------------------------------------------------------------------
// K1: merged QKV projection. 512 blocks x 256 thr (4 waves, 16-row tiles):
// 2 blocks/CU so barrier drains overlap the co-resident block's MFMAs.
// LDS x is DOUBLE-BUFFERED -> ONE barrier per c0i step (was 2).
// All 4 waves share the A-fragments (rows 0-15); wave wv owns col tile
// ctq=wv of each of q,k,v. W operands are direct global fragment loads
// (register double-buffered, L2-resident).
// ---------------------------------------------------------------------------
__global__ __launch_bounds__(256) void qkv_proj_kernel(
    const float* __restrict__ x, const short* __restrict__ wtf,
    short* __restrict__ qhp, short* __restrict__ qlp,
    short* __restrict__ khp, short* __restrict__ klp,
    short* __restrict__ vtp)
{
    __shared__ __align__(16) short xh[2][16 * 64], xl[2][16 * 64];  // 2x2 KB each

    const int t = threadIdx.x, L = t & 63, wv = t >> 6;
    const int R0 = blockIdx.x * 16;
    const int ctq = wv;                    // wave's 16-col tile

    f32x4 acc[3];
    #pragma unroll
    for (int j = 0; j < 3; ++j) acc[j] = {0.f, 0.f, 0.f, 0.f};

    // x staging: 16 rows x 64 cols fp32 per step; thread = one float4
    const int xrow = t >> 4, xc4 = t & 15;
    const float* xp = x + (size_t)(R0 + xrow) * C_ + xc4 * 4;
    float4 xa;
    auto loadX = [&](int c0) { xa = *(const float4*)(xp + c0); };

    const int c8 = xc4 >> 1, xhalf = xc4 & 1;
    const int slot = xrow * 64 + ((c8 ^ (xrow & 7)) * 8) + xhalf * 4;
    auto stageX = [&](int buf) {
        float vs[4] = {xa.x, xa.y, xa.z, xa.w};
        short4 vh, vl;
        short* vhp = (short*)&vh; short* vlp = (short*)&vl;
        #pragma unroll
        for (int e = 0; e < 4; ++e) {
            short hh = f2bf(vs[e]);
            vhp[e] = hh;
            vlp[e] = f2bf(vs[e] - bf2f(hh));
        }
        *(short4*)&xh[buf][slot] = vh;
        *(short4*)&xl[buf][slot] = vl;
    };

    // W fragments: slots 0=qh 1=ql 2=kh 3=kl 4=vh
    const size_t lo8 = (size_t)L * 8;
    auto loadWF = [&](int c0i, int kc, bf16x8* w) {
        w[0] = *(const bf16x8*)(wtf + (size_t)((((ctq + 0) * 2 + 0) * 16 + c0i) * 2 + kc) * 512 + lo8);
        w[1] = *(const bf16x8*)(wtf + (size_t)((((ctq + 0) * 2 + 1) * 16 + c0i) * 2 + kc) * 512 + lo8);
        w[2] = *(const bf16x8*)(wtf + (size_t)((((ctq + 4) * 2 + 0) * 16 + c0i) * 2 + kc) * 512 + lo8);
        w[3] = *(const bf16x8*)(wtf + (size_t)((((ctq + 4) * 2 + 1) * 16 + c0i) * 2 + kc) * 512 + lo8);
        w[4] = *(const bf16x8*)(wtf + (size_t)((((ctq + 8) * 2 + 0) * 16 + c0i) * 2 + kc) * 512 + lo8);
    };

    bf16x8 wf0[5], wf1[5];
    const int arow = L & 15;

    // prologue: stage step 0 into buf0, prefetch step 1
    loadX(0);
    loadWF(0, 0, wf0);
    stageX(0);
    loadX(64);
    __syncthreads();

    for (int c0i = 0; c0i < 16; ++c0i) {
        const int cur = c0i & 1;
        // stage next step into the other buffer (xa holds step c0i+1 data)
        if (c0i < 15) {
            stageX(cur ^ 1);
            if (c0i < 14) loadX((c0i + 2) * 64);
        }
        // ---- kc = 0: compute with wf0, prefetch wf1
        loadWF(c0i, 1, wf1);
        {
            int ch = 0 * 4 + (L >> 4);
            int off = arow * 64 + ((ch ^ (arow & 7)) * 8);
            bf16x8 axh = *(const bf16x8*)&xh[cur][off];
            bf16x8 axl = *(const bf16x8*)&xl[cur][off];
            acc[0] = MFMA_BF16(axl, wf0[0], acc[0]);
            acc[0] = MFMA_BF16(axh, wf0[1], acc[0]);
            acc[0] = MFMA_BF16(axh, wf0[0], acc[0]);
            acc[1] = MFMA_BF16(axl, wf0[2], acc[1]);
            acc[1] = MFMA_BF16(axh, wf0[3], acc[1]);
            acc[1] = MFMA_BF16(axh, wf0[2], acc[1]);
            acc[2] = MFMA_BF16(wf0[4], axh, acc[2]);   // v swapped -> D[h][t]
        }
        // ---- kc = 1: compute with wf1, prefetch next step's wf0
        if (c0i < 15) loadWF(c0i + 1, 0, wf0);
        {
            int ch = 1 * 4 + (L >> 4);
            int off = arow * 64 + ((ch ^ (arow & 7)) * 8);
            bf16x8 axh = *(const bf16x8*)&xh[cur][off];
            bf16x8 axl = *(const bf16x8*)&xl[cur][off];
            acc[0] = MFMA_BF16(axl, wf1[0], acc[0]);
            acc[0] = MFMA_BF16(axh, wf1[1], acc[0]);
            acc[0] = MFMA_BF16(axh, wf1[0], acc[0]);
            acc[1] = MFMA_BF16(axl, wf1[2], acc[1]);
            acc[1] = MFMA_BF16(axh, wf1[3], acc[1]);
            acc[1] = MFMA_BF16(axh, wf1[2], acc[1]);
            acc[2] = MFMA_BF16(wf1[4], axh, acc[2]);
        }
        __syncthreads();
    }

    // ---- epilogue
    const int quad = L >> 4;
    #pragma unroll
    for (int r = 0; r < 4; ++r) {
        int row = R0 + quad * 4 + r;
        int h = ctq * 16 + (L & 15);
        float vq = acc[0][r] * 8.f;
        short hq = f2bf(vq);
        qhp[(size_t)row * HD_ + h] = hq;
        qlp[(size_t)row * HD_ + h] = f2bf(vq - bf2f(hq));
        float vk = acc[1][r];
        short hk = f2bf(vk);
        khp[(size_t)row * HD_ + h] = hk;
        klp[(size_t)row * HD_ + h] = f2bf(vk - bf2f(hk));
        int d = ctq * 16 + quad * 4 + r;
        int tt = R0 + (L & 15);
        int bb = tt >> 11, tl = tt & (T_ - 1);
        vtp[(size_t)(bb * 64 + d) * T_ + tl] = f2bf(acc[2][r]);
    }
}

// ---------------------------------------------------------------------------
// K2a: full-row softmax stats + score spill. NO LDS staging; zero barriers
// in the jt loop; K frags register double-buffered. Causal-needed tiles
// spilled f32 (L3-resident).
// ---------------------------------------------------------------------------
__global__ __launch_bounds__(256) void stats_kernel(
    const short* __restrict__ qhp, const short* __restrict__ qlp,
    const short* __restrict__ khp, const short* __restrict__ klp,
    float* __restrict__ pm, float* __restrict__ sc)
{
    __shared__ float red[4 * 64 * 2];

    const int t = threadIdx.x, L = t & 63, wv = t >> 6;
    const int bt = blockIdx.x, seg = blockIdx.y, b = blockIdx.z;
    const int R0 = bt * 64, S0 = seg * 256;

    bf16x8 qfh[4][2], qfl[4][2];
    #pragma unroll
    for (int rt = 0; rt < 4; ++rt)
        #pragma unroll
        for (int dc = 0; dc < 2; ++dc) {
            int row = R0 + rt * 16 + (L & 15);
            size_t off = ((size_t)b * T_ + row) * HD_ + dc * 32 + (L >> 4) * 8;
            qfh[rt][dc] = *(const bf16x8*)(qhp + off);
            qfl[rt][dc] = *(const bf16x8*)(qlp + off);
        }

    float ml[4][4], ll[4][4];
    #pragma unroll
    for (int rt = 0; rt < 4; ++rt)
        #pragma unroll
        for (int r = 0; r < 4; ++r) { ml[rt][r] = -1e30f; ll[rt][r] = 0.f; }

    const int colL = wv * 16 + (L & 15);
    const short* kbh = khp + ((size_t)b * T_ + S0 + colL) * HD_;
    const short* kbl = klp + ((size_t)b * T_ + S0 + colL) * HD_;
    const int cho = (L >> 4) * 8;

    bf16x8 kfh[2][2], kfl[2][2];
    auto loadK = [&](int jt, bf16x8 kh[2], bf16x8 kl[2]) {
        #pragma unroll
        for (int dc = 0; dc < 2; ++dc) {
            kh[dc] = *(const bf16x8*)(kbh + (size_t)jt * 64 * HD_ + dc * 32 + cho);
            kl[dc] = *(const bf16x8*)(kbl + (size_t)jt * 64 * HD_ + dc * 32 + cho);
        }
    };
    loadK(0, kfh[0], kfl[0]);

    #pragma unroll
    for (int jt = 0; jt < 4; ++jt) {
        const int cb = jt & 1;
        if (jt < 3) loadK(jt + 1, kfh[cb ^ 1], kfl[cb ^ 1]);
        const bool doStore = (S0 + jt * 64) <= (R0 + 63);   // causal-needed tile
        #pragma unroll
        for (int rt = 0; rt < 4; ++rt) {
            f32x4 s = {0.f, 0.f, 0.f, 0.f};
            #pragma unroll
            for (int dc = 0; dc < 2; ++dc) {
                s = MFMA_BF16(qfl[rt][dc], kfh[cb][dc], s);
                s = MFMA_BF16(qfh[rt][dc], kfl[cb][dc], s);
                s = MFMA_BF16(qfh[rt][dc], kfh[cb][dc], s);
            }
            if (doStore) {
                #pragma unroll
                for (int r = 0; r < 4; ++r) {
                    int row = R0 + rt * 16 + (L >> 4) * 4 + r;
                    sc[((size_t)b * T_ + row) * T_ + S0 + jt * 64 + colL] = s[r];
                }
            }
            #pragma unroll
            for (int r = 0; r < 4; ++r) {
                float mn = fmaxf(ml[rt][r], s[r]);
                ll[rt][r] = ll[rt][r] * __expf(ml[rt][r] - mn) + __expf(s[r] - mn);
                ml[rt][r] = mn;
            }
        }
    }
    // merge the 16 columns within each wave
    #pragma unroll
    for (int off = 1; off < 16; off <<= 1)
        #pragma unroll
        for (int rt = 0; rt < 4; ++rt)
            #pragma unroll
            for (int r = 0; r < 4; ++r) {
                float mo = __shfl_xor(ml[rt][r], off, 64);
                float lo = __shfl_xor(ll[rt][r], off, 64);
                float mn = fmaxf(ml[rt][r], mo);
                ll[rt][r] = ll[rt][r] * __expf(ml[rt][r] - mn) + lo * __expf(mo - mn);
                ml[rt][r] = mn;
            }
    if ((L & 15) == 0) {
        #pragma unroll
        for (int rt = 0; rt < 4; ++rt)
            #pragma unroll
            for (int r = 0; r < 4; ++r) {
                int row = rt * 16 + (L >> 4) * 4 + r;
                red[(wv * 64 + row) * 2 + 0] = ml[rt][r];
                red[(wv * 64 + row) * 2 + 1] = ll[rt][r];
            }
    }
    __syncthreads();
    if (t < 64) {
        float M = red[t * 2], S = red[t * 2 + 1];
        #pragma unroll
        for (int w = 1; w < 4; ++w) {
            float mo = red[(w * 64 + t) * 2], lo = red[(w * 64 + t) * 2 + 1];
            float mn = fmaxf(M, mo);
            S = S * __expf(M - mn) + lo * __expf(mo - mn);
            M = mn;
        }
        size_t o = ((size_t)((b * 32 + bt) * 8 + seg) * 64 + t) * 2;
        pm[o] = M;
        pm[o + 1] = S;
    }
}

// ---------------------------------------------------------------------------
// K2c: causal second softmax + PV, streaming spilled scores with a manual
// 2-deep register pipeline (loads for jt+1 fly under jt's exp+MFMA).
// 1/S folded into the exponent: pvv = exp(s - (m + ln S)).
// stat_merge folded into the prologue.
// ---------------------------------------------------------------------------
__global__ __launch_bounds__(256) void pv_kernel(
    const float* __restrict__ sc, const short* __restrict__ vtp,
    const float* __restrict__ pm, float* __restrict__ out)
{
    __shared__ float ored[4][16][64];   // 16 KB: per-wave PV partials
    __shared__ float dred[4][16];
    __shared__ float msl[16];

    const int t = threadIdx.x, L = t & 63, wv = t >> 6;
    const int b = blockIdx.x & 3;
    const int i = blockIdx.x >> 2;
    const int p = (i < 64) ? (127 - i) : (i - 64);
    const int T0 = p * 16;

    if (t < 16) {                       // folded stat_merge for these 16 rows
        int row = T0 + t;
        int bt = row >> 6, rr = row & 63;
        float M = -1e30f, S = 0.f;
        #pragma unroll
        for (int seg = 0; seg < 8; ++seg) {
            size_t o = ((size_t)((b * 32 + bt) * 8 + seg) * 64 + rr) * 2;
            float mo = pm[o], lo = pm[o + 1];
            float mn = fmaxf(M, mo);
            S = S * __expf(M - mn) + lo * __expf(mo - mn);
            M = mn;
        }
        msl[t] = M + __logf(S);         // pvv = exp(s - msl)
    }
    __syncthreads();

    const int row = T0 + (L & 15);
    const float mls = msl[L & 15];
    const float* srow = sc + ((size_t)b * T_ + row) * T_;
    const short* vb = vtp + (size_t)b * 64 * T_;
    const int nJ = (T0 + 143) >> 7;     // ceil((T0+16)/128)
    const int cq = (L >> 4) * 8;

    f32x4 ov[4];
    #pragma unroll
    for (int dt = 0; dt < 4; ++dt) ov[dt] = {0.f, 0.f, 0.f, 0.f};
    float dn = 0.f;

    float4 sa0, sa1, sb0, sb1;
    bf16x8 va0, va1, va2, va3, vb0, vb1, vb2, vb3;

#define LDS_(jt, s0, s1) { int c0_ = (jt) * 128 + wv * 32 + cq;                  \
        s0 = *(const float4*)(srow + c0_); s1 = *(const float4*)(srow + c0_ + 4); }
#define LDV_(jt, v0, v1, v2, v3) { int c0_ = (jt) * 128 + wv * 32 + cq;          \
        v0 = *(const bf16x8*)(vb + (size_t)( 0 + (L & 15)) * T_ + c0_);          \
        v1 = *(const bf16x8*)(vb + (size_t)(16 + (L & 15)) * T_ + c0_);          \
        v2 = *(const bf16x8*)(vb + (size_t)(32 + (L & 15)) * T_ + c0_);          \
        v3 = *(const bf16x8*)(vb + (size_t)(48 + (L & 15)) * T_ + c0_); }
#define BODY_(jt, s0, s1, v0, v1, v2, v3) {                                      \
        const int c0_ = (jt) * 128 + wv * 32 + cq;                               \
        float vs_[8] = {s0.x, s0.y, s0.z, s0.w, s1.x, s1.y, s1.z, s1.w};         \
        bf16x8 ef_;                                                              \
        _Pragma("unroll")                                                        \
        for (int e = 0; e < 8; ++e) {                                            \
            float pvv = __expf(vs_[e] - mls);                                    \
            float evv = (c0_ + e <= row) ? __expf(pvv) : 0.f;                    \
            dn += evv;                                                           \
            ef_[e] = f2bf(evv);                                                  \
        }                                                                        \
        ov[0] = MFMA_BF16(ef_, v0, ov[0]);                                       \
        ov[1] = MFMA_BF16(ef_, v1, ov[1]);                                       \
        ov[2] = MFMA_BF16(ef_, v2, ov[2]);                                       \
        ov[3] = MFMA_BF16(ef_, v3, ov[3]); }

    LDS_(0, sa0, sa1)
    LDV_(0, va0, va1, va2, va3)
    int jt = 0;
    for (; jt + 2 <= nJ; jt += 2) {
        LDS_(jt + 1, sb0, sb1)
        LDV_(jt + 1, vb0, vb1, vb2, vb3)
        BODY_(jt, sa0, sa1, va0, va1, va2, va3)
        if (jt + 2 < nJ) {
            LDS_(jt + 2, sa0, sa1)
            LDV_(jt + 2, va0, va1, va2, va3)
        }
        BODY_(jt + 1, sb0, sb1, vb0, vb1, vb2, vb3)
    }
    if (jt < nJ) {
        BODY_(jt, sa0, sa1, va0, va1, va2, va3)
    }
#undef LDS_
#undef LDV_
#undef BODY_

    dn += __shfl_xor(dn, 16, 64);
    dn += __shfl_xor(dn, 32, 64);
    if (L < 16) dred[wv][L] = dn;
    #pragma unroll
    for (int dt = 0; dt < 4; ++dt)
        #pragma unroll
        for (int r = 0; r < 4; ++r)
            ored[wv][(L >> 4) * 4 + r][dt * 16 + (L & 15)] = ov[dt][r];
    __syncthreads();

    const int orow = t >> 4, d0 = (t & 15) * 4;
    float D = dred[0][orow] + dred[1][orow] + dred[2][orow] + dred[3][orow];
    float di = 1.f / D;
    float4 o;
    o.x = (ored[0][orow][d0 + 0] + ored[1][orow][d0 + 0]
         + ored[2][orow][d0 + 0] + ored[3][orow][d0 + 0]) * di;
    o.y = (ored[0][orow][d0 + 1] + ored[1][orow][d0 + 1]
         + ored[2][orow][d0 + 1] + ored[3][orow][d0 + 1]) * di;
    o.z = (ored[0][orow][d0 + 2] + ored[1][orow][d0 + 2]
         + ored[2][orow][d0 + 2] + ored[3][orow][d0 + 2]) * di;
    o.w = (ored[0][orow][d0 + 3] + ored[1][orow][d0 + 3]
         + ored[2][orow][d0 + 3] + ored[3][orow][d0 + 3]) * di;
    *(float4*)(out + ((size_t)b * T_ + T0 + orow) * HD_ + d0) = o;
}

// ---------------------------------------------------------------------------
extern "C" void kernel_launch(void* const* d_in, const int* in_sizes, int n_in,
                              void* d_out, int out_size, void* d_ws, size_t ws_size,
                              hipStream_t stream) {
    (void)in_sizes; (void)n_in; (void)out_size; (void)ws_size;
    const float* x  = (const float*)d_in[0];
    const float* Wq = (const float*)d_in[1];
    const float* Wk = (const float*)d_in[2];
    const float* Wv = (const float*)d_in[3];
    float* outp = (float*)d_out;

    // ws layout:
    //   [0, 768K)        wt   (W fragment buffer; dead after proj)
    //   [0, 512K)        pm   (stats partials, 8 segs; reuses wt region)
    //   [768K, 5.75M)    qh/ql/kh/kl/vt
    //   [8M, 72M)        sc   scores f32 [4][2048][2048] (L3-resident)
    char* ws = (char*)d_ws;
    short* wt  = (short*)ws;
    float* pm  = (float*)ws;
    short* qh = (short*)(ws + 786432);
    short* ql = (short*)(ws + 786432 + 1048576);
    short* kh = (short*)(ws + 786432 + 2 * 1048576);
    short* kl = (short*)(ws + 786432 + 3 * 1048576);
    short* vt = (short*)(ws + 786432 + 4 * 1048576);
    float* sc = (float*)(ws + 8388608);

    prep_w_kernel<<<dim3(16, 3), 256, 0, stream>>>(Wq, Wk, Wv, wt);
    qkv_proj_kernel<<<dim3(512), 256, 0, stream>>>(x, wt, qh, ql, kh, kl, vt);
    stats_kernel<<<dim3(32, 8, 4), 256, 0, stream>>>(qh, ql, kh, kl, pm, sc);
    pv_kernel<<<dim3(512), 256, 0, stream>>>(sc, vt, pm, outp);
}